// Round 3
// baseline (475.158 us; speedup 1.0000x reference)
//
#include <hip/hip_runtime.h>

typedef float f2 __attribute__((ext_vector_type(2)));
typedef float f4 __attribute__((ext_vector_type(4)));

static __device__ __forceinline__ f2 vmax2(f2 a, f2 b) {
  f2 r;
  r.x = fmaxf(a.x, b.x); r.y = fmaxf(a.y, b.y);
  return r;
}
static __device__ __forceinline__ f2 vexp2(f2 a) {
  f2 r;
  r.x = __builtin_amdgcn_exp2f(a.x);
  r.y = __builtin_amdgcn_exp2f(a.y);
  return r;
}

// Grid: 8 (b) x 128 (h) x 4 (channel chunk) = 4096 blocks, 256 threads.
// Lane w = t & 127 (coalesced), cg = t >> 7. Each thread computes 8 channels:
// c = cc*16 + cg*8 + i. launch_bounds(256,8) pins VGPR<=64 so 8 waves/SIMD
// are resident; TLP hides the per-iteration LDS window re-reads.
__global__ __launch_bounds__(256, 8) void stem_kernel(
    const float* __restrict__ x,    // [8,3,128,128]
    const float* __restrict__ qwp,  // [64,3]
    const float* __restrict__ kwp,  // [64,3]
    const float* __restrict__ vwp,  // [64,3]
    const float* __restrict__ ea,   // [64,128]  (c, w)
    const float* __restrict__ eb,   // [64,128]  (c, h)
    const float* __restrict__ em,   // [64,128,128] (c, h, w)
    float* __restrict__ out)        // [8,64,128,128]
{
  // xt[cin][wp][r]: padded col wp in [0,132), r = 0..3 <-> source row h-2+r
  __shared__ float xt[3][132][4];

  const int blk = blockIdx.x;
  const int cc = blk & 3;          // channel chunk: channels [cc*16, cc*16+16)
  const int h  = (blk >> 2) & 127;
  const int b  = blk >> 9;
  const int t  = threadIdx.x;

  // Stage the 12 needed source rows (3 cin x 4 rows), zero-padded, coalesced.
  for (int idx = t; idx < 3 * 4 * 132; idx += 256) {
    int wp  = idx % 132;
    int rem = idx / 132;      // cin*4 + r
    int rr  = rem & 3;
    int cin = rem >> 2;
    int sr = h - 2 + rr;
    int sc = wp - 2;
    float val = 0.0f;
    if ((unsigned)sr < 128u && (unsigned)sc < 128u)
      val = x[((b * 3 + cin) * 128 + sr) * 128 + sc];
    xt[cin][wp][rr] = val;
  }
  __syncthreads();

  const int w  = t & 127;
  const int cg = t >> 7;                 // wave-uniform
  const float LOG2E = 1.4426950408889634f;

  // x window: cols w..w+3, rows 0..3, 3 cin, as float2 pairs (rows 01 / 23)
  // to invite v_pk_*_f32 dual-issue. xw[cin][2j] = rows 0-1 of col w+j.
  f2 xw[3][8];
#pragma unroll
  for (int j = 0; j < 4; ++j) {
#pragma unroll
    for (int ci = 0; ci < 3; ++ci) {
      f4 tmp = *(const f4*)(&xt[ci][w + j][0]);
      xw[ci][2 * j]     = f2{tmp.x, tmp.y};
      xw[ci][2 * j + 1] = f2{tmp.z, tmp.w};
    }
  }

  const int base_c = cc * 16 + cg * 8;
#pragma unroll 1
  for (int i = 0; i < 8; ++i) {
    const int c = __builtin_amdgcn_readfirstlane(base_c + i);  // -> s_loads

    const float kwa = kwp[c * 3 + 0], kwb = kwp[c * 3 + 1], kwc = kwp[c * 3 + 2];
    const float vwa = vwp[c * 3 + 0], vwb = vwp[c * 3 + 1], vwc = vwp[c * 3 + 2];
    const float qwa = qwp[c * 3 + 0], qwb = qwp[c * 3 + 1], qwc = qwp[c * 3 + 2];

    // k,v taps at the 16 window positions (8 f2's: col j = u>>1, rows 2*(u&1))
    f2 kk[8], vv[8];
#pragma unroll
    for (int u = 0; u < 8; ++u) {
      kk[u] = kwa * xw[0][u] + kwb * xw[1][u] + kwc * xw[2][u];
      vv[u] = vwa * xw[0][u] + vwb * xw[1][u] + vwc * xw[2][u];
    }
    // q at (h,w): col j=2, row r=2 -> u=5, component .x
    const float q = qwa * xw[0][5].x + qwb * xw[1][5].x + qwc * xw[2][5].x;

    // s' = (ea + eb) * em * log2(e): scalar shared by all 16 taps
    const float sp =
        (ea[c * 128 + w] + eb[c * 128 + h]) * em[(c * 128 + h) * 128 + w] * LOG2E;

    // embedding logits (log2 domain): tl = s' * v^2
    f2 tl[8];
#pragma unroll
    for (int u = 0; u < 8; ++u) tl[u] = (sp * vv[u]) * vv[u];

    f2 mm = vmax2(vmax2(vmax2(tl[0], tl[1]), vmax2(tl[2], tl[3])),
                  vmax2(vmax2(tl[4], tl[5]), vmax2(tl[6], tl[7])));
    const float tmax = fmaxf(mm.x, mm.y);

    // e_t = 2^(tl - tmax); normalization folded into q below
    f2 e[8];
#pragma unroll
    for (int u = 0; u < 8; ++u) e[u] = vexp2(tl[u] - tmax);

    f2 se = ((e[0] + e[1]) + (e[2] + e[3])) + ((e[4] + e[5]) + (e[6] + e[7]));
    const float sum_e = se.x + se.y;
    const float qs = q * LOG2E * __builtin_amdgcn_rcpf(sum_e);

    // att logits z = qs * k * e  (|z| <~ 4 -> no max-subtraction needed)
    f2 p[8];
#pragma unroll
    for (int u = 0; u < 8; ++u) p[u] = vexp2((qs * kk[u]) * e[u]);

    f2 ps = ((p[0] + p[1]) + (p[2] + p[3])) + ((p[4] + p[5]) + (p[6] + p[7]));
    f2 pv = p[0] * vv[0];
#pragma unroll
    for (int u = 1; u < 8; ++u) pv = pv + p[u] * vv[u];

    const float denom = ps.x + ps.y;
    const float numer = pv.x + pv.y;

    out[((b * 64 + c) * 128 + h) * 128 + w] =
        numer * __builtin_amdgcn_rcpf(denom);
  }
}

extern "C" void kernel_launch(void* const* d_in, const int* in_sizes, int n_in,
                              void* d_out, int out_size, void* d_ws, size_t ws_size,
                              hipStream_t stream) {
  const float* x  = (const float*)d_in[0];
  const float* qw = (const float*)d_in[1];
  const float* kw = (const float*)d_in[2];
  const float* vw = (const float*)d_in[3];
  const float* ea = (const float*)d_in[4];
  const float* eb = (const float*)d_in[5];
  const float* em = (const float*)d_in[6];
  float* out = (float*)d_out;

  stem_kernel<<<dim3(8 * 128 * 4), dim3(256), 0, stream>>>(x, qw, kw, vw, ea, eb, em, out);
}

// Round 4
// 58.801 us; speedup vs baseline: 8.0808x; 8.0808x over previous
//
#include <hip/hip_runtime.h>

typedef float f2 __attribute__((ext_vector_type(2)));
typedef float f4 __attribute__((ext_vector_type(4)));

static __device__ __forceinline__ f2 vmax2(f2 a, f2 b) {
  f2 r;
  r.x = fmaxf(a.x, b.x); r.y = fmaxf(a.y, b.y);
  return r;
}
static __device__ __forceinline__ f2 vexp2(f2 a) {
  f2 r;
  r.x = __builtin_amdgcn_exp2f(a.x);
  r.y = __builtin_amdgcn_exp2f(a.y);
  return r;
}

// Grid: 8(b) x 128(h) x 2(channel chunk) = 2048 blocks = exactly 8 blocks/CU.
// 256 threads: lane w = t & 127 (coalesced), cg = t >> 7.
// Each thread computes 16 channels: c = cc*32 + cg*16 + i.
// launch_bounds(256,4): R2-proven VGPR~60 (<=64 -> 8 waves/SIMD resident).
// NOTE: (256,8) forced a 32-VGPR budget and catastrophic scratch spills (R3).
__global__ __launch_bounds__(256, 4) void stem_kernel(
    const float* __restrict__ x,    // [8,3,128,128]
    const float* __restrict__ qwp,  // [64,3]
    const float* __restrict__ kwp,  // [64,3]
    const float* __restrict__ vwp,  // [64,3]
    const float* __restrict__ ea,   // [64,128]  (c, w)
    const float* __restrict__ eb,   // [64,128]  (c, h)
    const float* __restrict__ em,   // [64,128,128] (c, h, w)
    float* __restrict__ out)        // [8,64,128,128]
{
  // xt[cin][wp][r]: padded col wp in [0,132), r = 0..3 <-> source row h-2+r
  __shared__ float xt[3][132][4];

  const int blk = blockIdx.x;
  const int cc = blk & 1;            // channel chunk: [cc*32, cc*32+32)
  const int h  = (blk >> 1) & 127;
  const int b  = blk >> 8;
  const int t  = threadIdx.x;

  // Stage the 12 needed source rows (3 cin x 4 rows), zero-padded, coalesced.
  for (int idx = t; idx < 3 * 4 * 132; idx += 256) {
    int wp  = idx % 132;
    int rem = idx / 132;      // cin*4 + r
    int rr  = rem & 3;
    int cin = rem >> 2;
    int sr = h - 2 + rr;
    int sc = wp - 2;
    float val = 0.0f;
    if ((unsigned)sr < 128u && (unsigned)sc < 128u)
      val = x[((b * 3 + cin) * 128 + sr) * 128 + sc];
    xt[cin][wp][rr] = val;
  }
  __syncthreads();

  const int w  = t & 127;
  const int cg = t >> 7;                 // wave-uniform
  const float LOG2E = 1.4426950408889634f;

  const int base_c = cc * 32 + cg * 16;
#pragma unroll 1
  for (int i = 0; i < 16; ++i) {
    const int c = __builtin_amdgcn_readfirstlane(base_c + i);  // -> s_loads

    const float kwa = kwp[c * 3 + 0], kwb = kwp[c * 3 + 1], kwc = kwp[c * 3 + 2];
    const float vwa = vwp[c * 3 + 0], vwb = vwp[c * 3 + 1], vwc = vwp[c * 3 + 2];
    const float qwa = qwp[c * 3 + 0], qwb = qwp[c * 3 + 1], qwc = qwp[c * 3 + 2];

    // k,v taps at the 16 window positions, read window from LDS per iter.
    // u = 2*j + half: col j = u>>1, rows {0,1} (half=0) / {2,3} (half=1).
    f2 kk[8], vv[8];
    float q = 0.0f;
#pragma unroll
    for (int j = 0; j < 4; ++j) {
      f4 x0 = *(const f4*)(&xt[0][w + j][0]);
      f4 x1 = *(const f4*)(&xt[1][w + j][0]);
      f4 x2 = *(const f4*)(&xt[2][w + j][0]);
      f2 lo0 = f2{x0.x, x0.y}, hi0 = f2{x0.z, x0.w};
      f2 lo1 = f2{x1.x, x1.y}, hi1 = f2{x1.z, x1.w};
      f2 lo2 = f2{x2.x, x2.y}, hi2 = f2{x2.z, x2.w};
      kk[2 * j]     = kwa * lo0 + kwb * lo1 + kwc * lo2;
      kk[2 * j + 1] = kwa * hi0 + kwb * hi1 + kwc * hi2;
      vv[2 * j]     = vwa * lo0 + vwb * lo1 + vwc * lo2;
      vv[2 * j + 1] = vwa * hi0 + vwb * hi1 + vwc * hi2;
      if (j == 2)  // q at (h,w): col j=2, row r=2 -> hi*.x
        q = qwa * hi0.x + qwb * hi1.x + qwc * hi2.x;
    }

    // s' = (ea + eb) * em * log2(e): scalar shared by all 16 taps
    const float sp =
        (ea[c * 128 + w] + eb[c * 128 + h]) * em[(c * 128 + h) * 128 + w] * LOG2E;

    // embedding logits (log2 domain): tl = s' * v^2, then e = 2^(tl - tmax)
    // (e overwrites tl storage to cap live registers)
    f2 tl[8];
#pragma unroll
    for (int u = 0; u < 8; ++u) tl[u] = (sp * vv[u]) * vv[u];

    f2 mm = vmax2(vmax2(vmax2(tl[0], tl[1]), vmax2(tl[2], tl[3])),
                  vmax2(vmax2(tl[4], tl[5]), vmax2(tl[6], tl[7])));
    const float tmax = fmaxf(mm.x, mm.y);

#pragma unroll
    for (int u = 0; u < 8; ++u) tl[u] = vexp2(tl[u] - tmax);

    f2 se = ((tl[0] + tl[1]) + (tl[2] + tl[3])) + ((tl[4] + tl[5]) + (tl[6] + tl[7]));
    const float sum_e = se.x + se.y;
    const float qs = q * LOG2E * __builtin_amdgcn_rcpf(sum_e);

    // att logits z = qs * k * e (|z| <~ 4 -> no max-subtraction needed).
    // Accumulate ps/pv immediately so p never occupies more than 2 regs.
    f2 ps = f2{0.0f, 0.0f}, pv = f2{0.0f, 0.0f};
#pragma unroll
    for (int u = 0; u < 8; ++u) {
      f2 p = vexp2((qs * kk[u]) * tl[u]);
      ps = ps + p;
      pv = pv + p * vv[u];
    }

    const float denom = ps.x + ps.y;
    const float numer = pv.x + pv.y;

    out[((b * 64 + c) * 128 + h) * 128 + w] =
        numer * __builtin_amdgcn_rcpf(denom);
  }
}

extern "C" void kernel_launch(void* const* d_in, const int* in_sizes, int n_in,
                              void* d_out, int out_size, void* d_ws, size_t ws_size,
                              hipStream_t stream) {
  const float* x  = (const float*)d_in[0];
  const float* qw = (const float*)d_in[1];
  const float* kw = (const float*)d_in[2];
  const float* vw = (const float*)d_in[3];
  const float* ea = (const float*)d_in[4];
  const float* eb = (const float*)d_in[5];
  const float* em = (const float*)d_in[6];
  float* out = (float*)d_out;

  stem_kernel<<<dim3(8 * 128 * 2), dim3(256), 0, stream>>>(x, qw, kw, vw, ea, eb, em, out);
}